// Round 9
// baseline (570.094 us; speedup 1.0000x reference)
//
#include <hip/hip_runtime.h>

typedef __bf16 bf16;
typedef __bf16 bf16x8 __attribute__((ext_vector_type(8)));
typedef float f32x4 __attribute__((ext_vector_type(4)));

#define B_SZ   8
#define L_SEQ  1024
#define NH     16

// async global->LDS, 16B per lane; lds base wave-uniform, data lands at base+lane*16
__device__ __forceinline__ void lds_load16(bf16* lds, const bf16* g) {
  __builtin_amdgcn_global_load_lds(
      (const __attribute__((address_space(1))) void*)g,
      (__attribute__((address_space(3))) void*)lds, 16, 0, 0);
}

// load 8 contiguous f32 -> bf16x8
__device__ __forceinline__ bf16x8 cvt8(const float* __restrict__ p) {
  f32x4 a = *(const f32x4*)p;
  f32x4 b = *(const f32x4*)(p + 4);
  bf16x8 r;
  r[0] = (bf16)a[0]; r[1] = (bf16)a[1]; r[2] = (bf16)a[2]; r[3] = (bf16)a[3];
  r[4] = (bf16)b[0]; r[5] = (bf16)b[1]; r[6] = (bf16)b[2]; r[7] = (bf16)b[3];
  return r;
}

// Q,K,V f32 -> bf16 in one launch (blockIdx.y selects)
__global__ __launch_bounds__(256) void convert3_k(const float* p0, const float* p1,
                                                  const float* p2,
                                                  bf16* o0, bf16* o1, bf16* o2, int n8) {
  const float* in; bf16* out;
  switch (blockIdx.y) {
    case 0: in = p0; out = o0; break;
    case 1: in = p1; out = o1; break;
    default: in = p2; out = o2; break;
  }
  int i = blockIdx.x * 256 + threadIdx.x;
  if (i < n8) *(bf16x8*)&out[(size_t)i * 8] = cvt8(in + (size_t)i * 8);
}

// 4 weight matrices at once
__global__ __launch_bounds__(256) void convert4_k(const float* p0, const float* p1,
                                                  const float* p2, const float* p3,
                                                  bf16* o0, bf16* o1, bf16* o2, bf16* o3,
                                                  int n8) {
  const float* in; bf16* out;
  switch (blockIdx.y) {
    case 0: in = p0; out = o0; break;
    case 1: in = p1; out = o1; break;
    case 2: in = p2; out = o2; break;
    default: in = p3; out = o3; break;
  }
  int i = blockIdx.x * 256 + threadIdx.x;
  if (i < n8) *(bf16x8*)&out[(size_t)i * 8] = cvt8(in + (size_t)i * 8);
}

// mask (B,1,L,L) int32 -> bit-packed u64: word[(b*L+row)*16 + kt], bit j = mask!=0
__global__ __launch_bounds__(256) void pack_mask_k(const int* __restrict__ mask,
                                                   unsigned long long* __restrict__ out,
                                                   int nwords) {
  int w = blockIdx.x * 256 + threadIdx.x;
  if (w >= nwords) return;
  const int* base = mask + (size_t)w * 64;
  unsigned long long bits = 0;
  for (int j = 0; j < 64; j += 4) {
    int4 m4 = *(const int4*)(base + j);
    if (m4.x) bits |= 1ull << j;
    if (m4.y) bits |= 1ull << (j + 1);
    if (m4.z) bits |= 1ull << (j + 2);
    if (m4.w) bits |= 1ull << (j + 3);
  }
  out[w] = bits;
}

// ---------------------------------------------------------------------------
// Fused Q/K/V projection GEMMs (proven): blockIdx.z selects.
// ---------------------------------------------------------------------------
__global__ __launch_bounds__(256) void gemm3(const bf16* __restrict__ aq,
                                             const bf16* __restrict__ ak,
                                             const bf16* __restrict__ av,
                                             const bf16* __restrict__ wq,
                                             const bf16* __restrict__ wk,
                                             const bf16* __restrict__ wv,
                                             const float* __restrict__ bq,
                                             const float* __restrict__ bk,
                                             const float* __restrict__ bv,
                                             bf16* __restrict__ oq,
                                             bf16* __restrict__ ok,
                                             bf16* __restrict__ ov) {
  const bf16* A; const bf16* W; const float* bias; bf16* out;
  switch (blockIdx.z) {
    case 0: A = aq; W = wq; bias = bq; out = oq; break;
    case 1: A = ak; W = wk; bias = bk; out = ok; break;
    default: A = av; W = wv; bias = bv; out = ov; break;
  }
  const int K = 1024, N = 1024;
  const int tid  = threadIdx.x;
  const int wave = tid >> 6;
  const int lane = tid & 63;
  const int quad = lane >> 4;
  const int l16  = lane & 15;
  const int wr   = wave >> 1;
  const int wc   = wave & 1;
  const int bm   = blockIdx.y * 128;
  const int bn   = blockIdx.x * 128;

  __shared__ __align__(16) bf16 a_s[128 * 64];
  __shared__ __align__(16) bf16 b_s[128 * 64];

  const int lrow = lane >> 3;
  const int lcol = (lane & 7) * 8;

  f32x4 acc[4][4] = {};

  for (int kt = 0; kt < K; kt += 64) {
    __syncthreads();
    for (int i = 0; i < 4; i++) {
      int c = wave * 4 + i;
      int row = c * 8 + lrow;
      lds_load16(&a_s[c * 512], &A[(size_t)(bm + row) * K + kt + lcol]);
      lds_load16(&b_s[c * 512], &W[(size_t)(bn + row) * K + kt + lcol]);
    }
    __syncthreads();

    for (int ks = 0; ks < 2; ks++) {
      bf16x8 af[4], bfr[4];
      for (int mt = 0; mt < 4; mt++)
        af[mt] = *(const bf16x8*)&a_s[(wr * 64 + mt * 16 + l16) * 64 + ks * 32 + quad * 8];
      for (int nt = 0; nt < 4; nt++)
        bfr[nt] = *(const bf16x8*)&b_s[(wc * 64 + nt * 16 + l16) * 64 + ks * 32 + quad * 8];
      for (int mt = 0; mt < 4; mt++)
        for (int nt = 0; nt < 4; nt++)
          acc[mt][nt] = __builtin_amdgcn_mfma_f32_16x16x32_bf16(af[mt], bfr[nt], acc[mt][nt], 0, 0, 0);
    }
  }

  for (int mt = 0; mt < 4; mt++) {
    for (int nt = 0; nt < 4; nt++) {
      int col = bn + wc * 64 + nt * 16 + l16;
      float bv2 = bias[col];
      for (int r = 0; r < 4; r++) {
        int i = bm + wr * 64 + mt * 16 + quad * 4 + r;
        out[(size_t)i * N + col] = (bf16)(acc[mt][nt][r] + bv2);
      }
    }
  }
}

// ---------------------------------------------------------------------------
// Final projection GEMM: out = A @ W^T + bias, f32 row-major out (to d_out).
// ---------------------------------------------------------------------------
__global__ __launch_bounds__(256) void gemm16(const bf16* __restrict__ A,
                                              const bf16* __restrict__ W,
                                              const float* __restrict__ bias,
                                              float* __restrict__ out,
                                              int M, int N, int K) {
  const int tid  = threadIdx.x;
  const int wave = tid >> 6;
  const int lane = tid & 63;
  const int quad = lane >> 4;
  const int l16  = lane & 15;
  const int wr   = wave >> 1;
  const int wc   = wave & 1;
  const int bm   = blockIdx.y * 128;
  const int bn   = blockIdx.x * 128;

  __shared__ __align__(16) bf16 a_s[128 * 64];
  __shared__ __align__(16) bf16 b_s[128 * 64];

  const int lrow = lane >> 3;
  const int lcol = (lane & 7) * 8;

  f32x4 acc[4][4] = {};

  for (int kt = 0; kt < K; kt += 64) {
    __syncthreads();
    for (int i = 0; i < 4; i++) {
      int c = wave * 4 + i;
      int row = c * 8 + lrow;
      lds_load16(&a_s[c * 512], &A[(size_t)(bm + row) * K + kt + lcol]);
      lds_load16(&b_s[c * 512], &W[(size_t)(bn + row) * K + kt + lcol]);
    }
    __syncthreads();

    for (int ks = 0; ks < 2; ks++) {
      bf16x8 af[4], bfr[4];
      for (int mt = 0; mt < 4; mt++)
        af[mt] = *(const bf16x8*)&a_s[(wr * 64 + mt * 16 + l16) * 64 + ks * 32 + quad * 8];
      for (int nt = 0; nt < 4; nt++)
        bfr[nt] = *(const bf16x8*)&b_s[(wc * 64 + nt * 16 + l16) * 64 + ks * 32 + quad * 8];
      for (int mt = 0; mt < 4; mt++)
        for (int nt = 0; nt < 4; nt++)
          acc[mt][nt] = __builtin_amdgcn_mfma_f32_16x16x32_bf16(af[mt], bfr[nt], acc[mt][nt], 0, 0, 0);
    }
  }

  for (int mt = 0; mt < 4; mt++) {
    for (int nt = 0; nt < 4; nt++) {
      int col = bn + wc * 64 + nt * 16 + l16;
      float bv = bias[col];
      for (int r = 0; r < 4; r++) {
        int i = bm + wr * 64 + mt * 16 + quad * 4 + r;
        out[(size_t)i * N + col] = acc[mt][nt][r] + bv;
      }
    }
  }
}

// ---------------------------------------------------------------------------
// t = T @ WT^T + bT.  T: 8192x64 f32, WT: 64x64 f32.  out: 8192x64 bf16.
// ---------------------------------------------------------------------------
__global__ __launch_bounds__(256) void t_proj(const float* __restrict__ T,
                                              const float* __restrict__ WT,
                                              const float* __restrict__ bT,
                                              bf16* __restrict__ tout) {
  const int tid  = threadIdx.x;
  const int wave = tid >> 6;
  const int lane = tid & 63;
  const int quad = lane >> 4;
  const int l16  = lane & 15;
  const int row0 = blockIdx.x * 64;

  __shared__ __align__(16) bf16 t_s[64][72];
  __shared__ __align__(16) bf16 w_s[64][72];

  for (int i = 0; i < 2; i++) {
    int c = tid + i * 256;
    int r = c >> 3;
    int cg = (c & 7) * 8;
    *(bf16x8*)&t_s[r][cg] = cvt8(T + (size_t)(row0 + r) * 64 + cg);
    *(bf16x8*)&w_s[r][cg] = cvt8(WT + (size_t)r * 64 + cg);
  }
  __syncthreads();

  f32x4 acc[4] = {};
  for (int ks = 0; ks < 2; ks++) {
    bf16x8 a = *(const bf16x8*)&t_s[wave * 16 + l16][ks * 32 + quad * 8];
    for (int nt = 0; nt < 4; nt++) {
      bf16x8 b = *(const bf16x8*)&w_s[nt * 16 + l16][ks * 32 + quad * 8];
      acc[nt] = __builtin_amdgcn_mfma_f32_16x16x32_bf16(a, b, acc[nt], 0, 0, 0);
    }
  }
  for (int nt = 0; nt < 4; nt++) {
    int col = nt * 16 + l16;
    float bv = bT[col];
    for (int r = 0; r < 4; r++) {
      int row = row0 + wave * 16 + quad * 4 + r;
      tout[(size_t)row * 64 + col] = (bf16)(acc[nt][r] + bv);
    }
  }
}

// ---------------------------------------------------------------------------
// Flash attention, q-tile=128 rows, 512 threads. 2x2 wave tiles:
// wave w: qg = w>>1 (32 q rows), kg = w&1 (32 keys / 32 dv cols).
// QK: 32q x 32k per wave -> k-frag reads halved (8 b128 vs 16).
// PV: 32q x 32dv per wave -> v-frag reads halved (4 vs 8); P is cross-wave
// -> extra barrier per kt. l-reduction cross-wave once at end via l_red.
// Q fragments register-resident; LDS ~46 KB -> 3 blocks/CU.
// ---------------------------------------------------------------------------
__global__ __launch_bounds__(512, 6) void attn(const bf16* __restrict__ qp,
                                               const bf16* __restrict__ kp,
                                               const bf16* __restrict__ vp,
                                               const bf16* __restrict__ tb,
                                               const unsigned long long* __restrict__ mb64,
                                               bf16* __restrict__ xout) {
  const int bh   = blockIdx.x;        // 0..127
  const int qt   = blockIdx.y;        // 0..7
  const int b    = bh >> 4;
  const int h    = bh & 15;
  const int tid  = threadIdx.x;
  const int wave = tid >> 6;          // 0..7
  const int lane = tid & 63;
  const int quad = lane >> 4;
  const int l16  = lane & 15;
  const int qg   = wave >> 1;         // 0..3: 32-q-row group
  const int kg   = wave & 1;          // 0..1: 32-key / 32-dv group

  __shared__ __align__(16) bf16 k_s[64][136];   // 17408 B
  __shared__ __align__(16) bf16 v_s[64][72];    //  9216 B  [dv][l]
  __shared__ __align__(16) bf16 p_s[128][72];   // 18432 B
  __shared__ float l_red[2][128];               //  1024 B  => 46080 total

  const bf16* qpb = qp + (size_t)(b * L_SEQ) * 1024 + h * 64;
  const bf16* kpb = kp + (size_t)(b * L_SEQ) * 1024 + h * 64;
  const bf16* vpb = vp + (size_t)(b * L_SEQ) * 1024 + h * 64;
  const bf16* tb0 = tb + (size_t)b * L_SEQ * 64;
  const unsigned long long* mrow = mb64 + (size_t)b * L_SEQ * 16;

  // q fragments in registers: qf[mt][ks], rows qg*32+mt*16+l16, d=ks*32+quad*8
  bf16x8 qf[2][4];
  for (int mt = 0; mt < 2; mt++) {
    int grow = qt * 128 + qg * 32 + mt * 16 + l16;
    qf[mt][0] = *(const bf16x8*)(qpb + (size_t)grow * 1024 + quad * 8);
    qf[mt][1] = *(const bf16x8*)(qpb + (size_t)grow * 1024 + 32 + quad * 8);
    qf[mt][2] = *(const bf16x8*)(tb0 + (size_t)grow * 64 + quad * 8);
    qf[mt][3] = *(const bf16x8*)(tb0 + (size_t)grow * 64 + 32 + quad * 8);
  }

  // staging index maps (k tile: 2 chunks/thread; v tile: 1 chunk/thread)
  const int kc0_row = tid >> 4,         kc0_cg = tid & 15;
  const int kc1_row = (tid + 512) >> 4, kc1_cg = (tid + 512) & 15;
  const int v_l = tid & 63, v_dvb = (tid >> 6) * 8;

  bf16x8 kr0, kr1, vr;
  {
    const bf16* s0 = (kc0_cg < 8) ? (kpb + (size_t)kc0_row * 1024 + kc0_cg * 8)
                                  : (tb0 + (size_t)kc0_row * 64 + (kc0_cg - 8) * 8);
    const bf16* s1 = (kc1_cg < 8) ? (kpb + (size_t)kc1_row * 1024 + kc1_cg * 8)
                                  : (tb0 + (size_t)kc1_row * 64 + (kc1_cg - 8) * 8);
    kr0 = *(const bf16x8*)s0;
    kr1 = *(const bf16x8*)s1;
    vr  = *(const bf16x8*)&vpb[(size_t)v_l * 1024 + v_dvb];
  }

  f32x4 o[2][2] = {};
  float l_part[2][4] = {};

  const float C = 0.12751781f;   // 1/sqrt(128) * log2(e)

  for (int kt = 0; kt < 16; kt++) {
    __syncthreads();   // all prior-iter LDS reads (QK k_s, PV p_s/v_s) done
    *(bf16x8*)&k_s[kc0_row][kc0_cg * 8] = kr0;
    *(bf16x8*)&k_s[kc1_row][kc1_cg * 8] = kr1;
    for (int j = 0; j < 8; j++) v_s[v_dvb + j][v_l] = vr[j];
    __syncthreads();

    // S tile 32q x 32k per wave (K=128 contraction)
    f32x4 s_acc[2][2] = {};
    for (int ks = 0; ks < 4; ks++) {
      bf16x8 kf[2];
      for (int nt = 0; nt < 2; nt++)
        kf[nt] = *(const bf16x8*)&k_s[kg * 32 + nt * 16 + l16][ks * 32 + quad * 8];
      for (int mt = 0; mt < 2; mt++)
        for (int nt = 0; nt < 2; nt++)
          s_acc[mt][nt] = __builtin_amdgcn_mfma_f32_16x16x32_bf16(qf[mt][ks], kf[nt], s_acc[mt][nt], 0, 0, 0);
    }

    // p = exp2(s*C) (masked -> 0); accumulate l partials; P -> LDS
    for (int mt = 0; mt < 2; mt++) {
      for (int r = 0; r < 4; r++) {
        int qrow = qt * 128 + qg * 32 + mt * 16 + quad * 4 + r;
        unsigned long long wsh = mrow[(size_t)qrow * 16 + kt] >> (kg * 32 + l16);
        for (int nt = 0; nt < 2; nt++) {
          float arg = s_acc[mt][nt][r] * C;
          if ((wsh >> (nt * 16)) & 1ull) arg = -1e9f;
          float p = __builtin_amdgcn_exp2f(arg);
          l_part[mt][r] += p;
          p_s[qg * 32 + mt * 16 + quad * 4 + r][kg * 32 + nt * 16 + l16] = (bf16)p;
        }
      }
    }

    // prefetch kt+1 while PV runs
    if (kt < 15) {
      int gl0 = (kt + 1) * 64;
      const bf16* s0 = (kc0_cg < 8) ? (kpb + (size_t)(gl0 + kc0_row) * 1024 + kc0_cg * 8)
                                    : (tb0 + (size_t)(gl0 + kc0_row) * 64 + (kc0_cg - 8) * 8);
      const bf16* s1 = (kc1_cg < 8) ? (kpb + (size_t)(gl0 + kc1_row) * 1024 + kc1_cg * 8)
                                    : (tb0 + (size_t)(gl0 + kc1_row) * 64 + (kc1_cg - 8) * 8);
      kr0 = *(const bf16x8*)s0;
      kr1 = *(const bf16x8*)s1;
      vr  = *(const bf16x8*)&vpb[(size_t)(gl0 + v_l) * 1024 + v_dvb];
    }

    __syncthreads();   // p_s visible to all waves (PV contracts all 64 keys)

    // O tile 32q x 32dv per wave (K=64 keys)
    for (int ks = 0; ks < 2; ks++) {
      bf16x8 af[2], vf[2];
      for (int mt = 0; mt < 2; mt++)
        af[mt] = *(const bf16x8*)&p_s[qg * 32 + mt * 16 + l16][ks * 32 + quad * 8];
      for (int nt = 0; nt < 2; nt++)
        vf[nt] = *(const bf16x8*)&v_s[kg * 32 + nt * 16 + l16][ks * 32 + quad * 8];
      for (int mt = 0; mt < 2; mt++)
        for (int nt = 0; nt < 2; nt++)
          o[mt][nt] = __builtin_amdgcn_mfma_f32_16x16x32_bf16(af[mt], vf[nt], o[mt][nt], 0, 0, 0);
    }
  }

  // cross-wave l reduction: intra-wave over l16 lanes, then combine kg halves
  for (int mt = 0; mt < 2; mt++) {
    for (int r = 0; r < 4; r++) {
      float s = l_part[mt][r];
      for (int off = 8; off >= 1; off >>= 1) s += __shfl_xor(s, off);
      if (l16 == 0) l_red[kg][qg * 32 + mt * 16 + quad * 4 + r] = s;
    }
  }
  __syncthreads();

  for (int mt = 0; mt < 2; mt++) {
    for (int nt = 0; nt < 2; nt++) {
      int col = h * 64 + kg * 32 + nt * 16 + l16;
      for (int r = 0; r < 4; r++) {
        int qi = qg * 32 + mt * 16 + quad * 4 + r;
        float inv_l = 1.f / fmaxf(l_red[0][qi] + l_red[1][qi], 1e-30f);
        int row = qt * 128 + qi;
        xout[((size_t)(b * L_SEQ + row)) * 1024 + col] = (bf16)(o[mt][nt][r] * inv_l);
      }
    }
  }
}

// ---------------------------------------------------------------------------
extern "C" void kernel_launch(void* const* d_in, const int* in_sizes, int n_in,
                              void* d_out, int out_size, void* d_ws, size_t ws_size,
                              hipStream_t stream) {
  const float* Q    = (const float*)d_in[0];
  const float* K    = (const float*)d_in[1];
  const float* V    = (const float*)d_in[2];
  const float* T    = (const float*)d_in[3];
  const int*   mask = (const int*)d_in[4];
  const float* WQ = (const float*)d_in[5];
  const float* bQ = (const float*)d_in[6];
  const float* WK = (const float*)d_in[7];
  const float* bK = (const float*)d_in[8];
  const float* WV = (const float*)d_in[9];
  const float* bV = (const float*)d_in[10];
  const float* WM = (const float*)d_in[11];
  const float* bM = (const float*)d_in[12];
  const float* WT = (const float*)d_in[13];
  const float* bT = (const float*)d_in[14];

  const size_t NE = (size_t)B_SZ * NH * L_SEQ * 64;  // 8388608
  bf16* ws16 = (bf16*)d_ws;
  bf16* qp = ws16;                    // bf16 8192x1024
  bf16* kp = ws16 + NE;
  bf16* vp = ws16 + 2 * NE;
  bf16* tb = ws16 + 3 * NE;           // 524288
  unsigned long long* mb64 = (unsigned long long*)(ws16 + 3 * NE + 524288);
  bf16* wq = ws16 + 3 * NE + 1048576;
  bf16* wk = wq + 1048576;
  bf16* wv = wk + 1048576;
  bf16* wm = wv + 1048576;
  bf16* av = wm + 1048576;            // gemm3 V-input scratch, then attn output
  bf16* aq = (bf16*)d_out;            // d_out as A-conversion scratch (dead after gemm3)
  bf16* ak = (bf16*)d_out + NE;
  bf16* xa = av;                      // attn bf16 output reuses av slot
  float* fout = (float*)d_out;        // final GEMM writes d_out directly

  dim3 blk(256);

  pack_mask_k<<<dim3(512), blk, 0, stream>>>(mask, mb64, 131072);
  convert4_k<<<dim3(512, 4), blk, 0, stream>>>(WQ, WK, WV, WM, wq, wk, wv, wm, 131072);
  t_proj<<<dim3(128), blk, 0, stream>>>(T, WT, bT, tb);

  convert3_k<<<dim3(4096, 3), blk, 0, stream>>>(Q, K, V, aq, ak, av, 1048576);
  gemm3<<<dim3(8, 64, 3), blk, 0, stream>>>(aq, ak, av, wq, wk, wv, bQ, bK, bV, qp, kp, vp);

  attn<<<dim3(128, 8), dim3(512), 0, stream>>>(qp, kp, vp, tb, mb64, xa);

  gemm16<<<dim3(8, 64), blk, 0, stream>>>(xa, wm, bM, fout, 8192, 1024, 1024);
}

// Round 10
// 410.690 us; speedup vs baseline: 1.3881x; 1.3881x over previous
//
#include <hip/hip_runtime.h>

typedef __bf16 bf16;
typedef __bf16 bf16x8 __attribute__((ext_vector_type(8)));
typedef float f32x4 __attribute__((ext_vector_type(4)));

#define B_SZ   8
#define L_SEQ  1024
#define NH     16

// async global->LDS, 16B per lane; lds base wave-uniform, data lands at base+lane*16
__device__ __forceinline__ void lds_load16(bf16* lds, const bf16* g) {
  __builtin_amdgcn_global_load_lds(
      (const __attribute__((address_space(1))) void*)g,
      (__attribute__((address_space(3))) void*)lds, 16, 0, 0);
}

// load 8 contiguous f32 -> bf16x8
__device__ __forceinline__ bf16x8 cvt8(const float* __restrict__ p) {
  f32x4 a = *(const f32x4*)p;
  f32x4 b = *(const f32x4*)(p + 4);
  bf16x8 r;
  r[0] = (bf16)a[0]; r[1] = (bf16)a[1]; r[2] = (bf16)a[2]; r[3] = (bf16)a[3];
  r[4] = (bf16)b[0]; r[5] = (bf16)b[1]; r[6] = (bf16)b[2]; r[7] = (bf16)b[3];
  return r;
}

// ---------------------------------------------------------------------------
// Fused prep: one launch for all preprocessing.
// grid (4096, 4), 256 threads:
//  y=0/1/2            : convert Q/K/V f32->bf16 (4096*256*8 = 8388608 elems exact)
//  y=3, bx<512        : pack mask -> u64 bitmask (512*256 = 131072 words exact)
//  y=3, 512<=bx<2560  : convert WQ/WK/WV/WM (512 blocks each, 131072 x8 exact)
//  y=3, 2560<=bx<2688 : t_proj = T @ WT^T + bT (128 blocks x 64 rows)
// ---------------------------------------------------------------------------
__global__ __launch_bounds__(256) void prep_k(
    const float* __restrict__ Q, const float* __restrict__ K, const float* __restrict__ V,
    bf16* __restrict__ aq, bf16* __restrict__ ak, bf16* __restrict__ av,
    const int* __restrict__ mask, unsigned long long* __restrict__ mb64,
    const float* __restrict__ WQ, const float* __restrict__ WK,
    const float* __restrict__ WV, const float* __restrict__ WM,
    bf16* __restrict__ wq, bf16* __restrict__ wk, bf16* __restrict__ wv, bf16* __restrict__ wm,
    const float* __restrict__ T, const float* __restrict__ WT,
    const float* __restrict__ bT, bf16* __restrict__ tbuf) {
  const int bx = blockIdx.x;
  const int y  = blockIdx.y;
  const int tid = threadIdx.x;

  __shared__ __align__(16) bf16 t_s[64][72];
  __shared__ __align__(16) bf16 w_s[64][72];

  if (y < 3) {
    const float* in = (y == 0) ? Q : (y == 1) ? K : V;
    bf16* out       = (y == 0) ? aq : (y == 1) ? ak : av;
    size_t i = (size_t)bx * 256 + tid;
    *(bf16x8*)&out[i * 8] = cvt8(in + i * 8);
    return;
  }

  if (bx < 512) {
    // mask bit-pack: word[(b*L+row)*16 + kt], bit j = mask[..][kt*64+j] != 0
    int w = bx * 256 + tid;
    const int* base = mask + (size_t)w * 64;
    unsigned long long bits = 0;
    for (int j = 0; j < 64; j += 4) {
      int4 m4 = *(const int4*)(base + j);
      if (m4.x) bits |= 1ull << j;
      if (m4.y) bits |= 1ull << (j + 1);
      if (m4.z) bits |= 1ull << (j + 2);
      if (m4.w) bits |= 1ull << (j + 3);
    }
    mb64[w] = bits;
  } else if (bx < 2560) {
    int wsel = (bx - 512) >> 9;
    const float* in = (wsel == 0) ? WQ : (wsel == 1) ? WK : (wsel == 2) ? WV : WM;
    bf16* out       = (wsel == 0) ? wq : (wsel == 1) ? wk : (wsel == 2) ? wv : wm;
    size_t i = (size_t)((bx - 512) & 511) * 256 + tid;
    *(bf16x8*)&out[i * 8] = cvt8(in + i * 8);
  } else if (bx < 2688) {
    // t = T @ WT^T + bT   (64 rows per block)
    const int wave = tid >> 6;
    const int lane = tid & 63;
    const int quad = lane >> 4;
    const int l16  = lane & 15;
    const int row0 = (bx - 2560) * 64;

    for (int i = 0; i < 2; i++) {
      int c = tid + i * 256;
      int r = c >> 3;
      int cg = (c & 7) * 8;
      *(bf16x8*)&t_s[r][cg] = cvt8(T + (size_t)(row0 + r) * 64 + cg);
      *(bf16x8*)&w_s[r][cg] = cvt8(WT + (size_t)r * 64 + cg);
    }
    __syncthreads();

    f32x4 acc[4] = {};
    for (int ks = 0; ks < 2; ks++) {
      bf16x8 a = *(const bf16x8*)&t_s[wave * 16 + l16][ks * 32 + quad * 8];
      for (int nt = 0; nt < 4; nt++) {
        bf16x8 b = *(const bf16x8*)&w_s[nt * 16 + l16][ks * 32 + quad * 8];
        acc[nt] = __builtin_amdgcn_mfma_f32_16x16x32_bf16(a, b, acc[nt], 0, 0, 0);
      }
    }
    for (int nt = 0; nt < 4; nt++) {
      int col = nt * 16 + l16;
      float bv = bT[col];
      for (int r = 0; r < 4; r++) {
        int row = row0 + wave * 16 + quad * 4 + r;
        tbuf[(size_t)row * 64 + col] = (bf16)(acc[nt][r] + bv);
      }
    }
  }
}

// ---------------------------------------------------------------------------
// Fused Q/K/V projection GEMMs (proven): blockIdx.z selects.
// ---------------------------------------------------------------------------
__global__ __launch_bounds__(256) void gemm3(const bf16* __restrict__ aq,
                                             const bf16* __restrict__ ak,
                                             const bf16* __restrict__ av,
                                             const bf16* __restrict__ wq,
                                             const bf16* __restrict__ wk,
                                             const bf16* __restrict__ wv,
                                             const float* __restrict__ bq,
                                             const float* __restrict__ bk,
                                             const float* __restrict__ bv,
                                             bf16* __restrict__ oq,
                                             bf16* __restrict__ ok,
                                             bf16* __restrict__ ov) {
  const bf16* A; const bf16* W; const float* bias; bf16* out;
  switch (blockIdx.z) {
    case 0: A = aq; W = wq; bias = bq; out = oq; break;
    case 1: A = ak; W = wk; bias = bk; out = ok; break;
    default: A = av; W = wv; bias = bv; out = ov; break;
  }
  const int K = 1024, N = 1024;
  const int tid  = threadIdx.x;
  const int wave = tid >> 6;
  const int lane = tid & 63;
  const int quad = lane >> 4;
  const int l16  = lane & 15;
  const int wr   = wave >> 1;
  const int wc   = wave & 1;
  const int bm   = blockIdx.y * 128;
  const int bn   = blockIdx.x * 128;

  __shared__ __align__(16) bf16 a_s[128 * 64];
  __shared__ __align__(16) bf16 b_s[128 * 64];

  const int lrow = lane >> 3;
  const int lcol = (lane & 7) * 8;

  f32x4 acc[4][4] = {};

  for (int kt = 0; kt < K; kt += 64) {
    __syncthreads();
    for (int i = 0; i < 4; i++) {
      int c = wave * 4 + i;
      int row = c * 8 + lrow;
      lds_load16(&a_s[c * 512], &A[(size_t)(bm + row) * K + kt + lcol]);
      lds_load16(&b_s[c * 512], &W[(size_t)(bn + row) * K + kt + lcol]);
    }
    __syncthreads();

    for (int ks = 0; ks < 2; ks++) {
      bf16x8 af[4], bfr[4];
      for (int mt = 0; mt < 4; mt++)
        af[mt] = *(const bf16x8*)&a_s[(wr * 64 + mt * 16 + l16) * 64 + ks * 32 + quad * 8];
      for (int nt = 0; nt < 4; nt++)
        bfr[nt] = *(const bf16x8*)&b_s[(wc * 64 + nt * 16 + l16) * 64 + ks * 32 + quad * 8];
      for (int mt = 0; mt < 4; mt++)
        for (int nt = 0; nt < 4; nt++)
          acc[mt][nt] = __builtin_amdgcn_mfma_f32_16x16x32_bf16(af[mt], bfr[nt], acc[mt][nt], 0, 0, 0);
    }
  }

  for (int mt = 0; mt < 4; mt++) {
    for (int nt = 0; nt < 4; nt++) {
      int col = bn + wc * 64 + nt * 16 + l16;
      float bv2 = bias[col];
      for (int r = 0; r < 4; r++) {
        int i = bm + wr * 64 + mt * 16 + quad * 4 + r;
        out[(size_t)i * N + col] = (bf16)(acc[mt][nt][r] + bv2);
      }
    }
  }
}

// ---------------------------------------------------------------------------
// Final projection GEMM: out = A @ W^T + bias, f32 row-major out (to d_out).
// ---------------------------------------------------------------------------
__global__ __launch_bounds__(256) void gemm16(const bf16* __restrict__ A,
                                              const bf16* __restrict__ W,
                                              const float* __restrict__ bias,
                                              float* __restrict__ out,
                                              int M, int N, int K) {
  const int tid  = threadIdx.x;
  const int wave = tid >> 6;
  const int lane = tid & 63;
  const int quad = lane >> 4;
  const int l16  = lane & 15;
  const int wr   = wave >> 1;
  const int wc   = wave & 1;
  const int bm   = blockIdx.y * 128;
  const int bn   = blockIdx.x * 128;

  __shared__ __align__(16) bf16 a_s[128 * 64];
  __shared__ __align__(16) bf16 b_s[128 * 64];

  const int lrow = lane >> 3;
  const int lcol = (lane & 7) * 8;

  f32x4 acc[4][4] = {};

  for (int kt = 0; kt < K; kt += 64) {
    __syncthreads();
    for (int i = 0; i < 4; i++) {
      int c = wave * 4 + i;
      int row = c * 8 + lrow;
      lds_load16(&a_s[c * 512], &A[(size_t)(bm + row) * K + kt + lcol]);
      lds_load16(&b_s[c * 512], &W[(size_t)(bn + row) * K + kt + lcol]);
    }
    __syncthreads();

    for (int ks = 0; ks < 2; ks++) {
      bf16x8 af[4], bfr[4];
      for (int mt = 0; mt < 4; mt++)
        af[mt] = *(const bf16x8*)&a_s[(wr * 64 + mt * 16 + l16) * 64 + ks * 32 + quad * 8];
      for (int nt = 0; nt < 4; nt++)
        bfr[nt] = *(const bf16x8*)&b_s[(wc * 64 + nt * 16 + l16) * 64 + ks * 32 + quad * 8];
      for (int mt = 0; mt < 4; mt++)
        for (int nt = 0; nt < 4; nt++)
          acc[mt][nt] = __builtin_amdgcn_mfma_f32_16x16x32_bf16(af[mt], bfr[nt], acc[mt][nt], 0, 0, 0);
    }
  }

  for (int mt = 0; mt < 4; mt++) {
    for (int nt = 0; nt < 4; nt++) {
      int col = bn + wc * 64 + nt * 16 + l16;
      float bv = bias[col];
      for (int r = 0; r < 4; r++) {
        int i = bm + wr * 64 + mt * 16 + quad * 4 + r;
        out[(size_t)i * N + col] = acc[mt][nt][r] + bv;
      }
    }
  }
}

// ---------------------------------------------------------------------------
// Flash attention (round-8 proven version, exact): q-tile=128 rows, 512 thr,
// q fragments in registers, no online max, deferred l-reduction, k/v register
// prefetch, XCD-swizzled grid (bh, qt). LDS 45 KB -> 3 blocks/CU.
// ---------------------------------------------------------------------------
__global__ __launch_bounds__(512, 6) void attn(const bf16* __restrict__ qp,
                                               const bf16* __restrict__ kp,
                                               const bf16* __restrict__ vp,
                                               const bf16* __restrict__ tb,
                                               const unsigned long long* __restrict__ mb64,
                                               bf16* __restrict__ xout) {
  const int bh   = blockIdx.x;        // 0..127
  const int qt   = blockIdx.y;        // 0..7
  const int b    = bh >> 4;
  const int h    = bh & 15;
  const int tid  = threadIdx.x;
  const int wave = tid >> 6;          // 0..7
  const int lane = tid & 63;
  const int quad = lane >> 4;
  const int l16  = lane & 15;

  __shared__ __align__(16) bf16 k_s[64][136];   // 17408 B
  __shared__ __align__(16) bf16 v_s[64][72];    //  9216 B  [dv][l]
  __shared__ __align__(16) bf16 p_s[128][72];   // 18432 B  => 45056 total, 3 blk/CU

  const bf16* qpb = qp + (size_t)(b * L_SEQ) * 1024 + h * 64;
  const bf16* kpb = kp + (size_t)(b * L_SEQ) * 1024 + h * 64;
  const bf16* vpb = vp + (size_t)(b * L_SEQ) * 1024 + h * 64;
  const bf16* tb0 = tb + (size_t)b * L_SEQ * 64;
  const unsigned long long* mrow = mb64 + (size_t)b * L_SEQ * 16;

  // q fragments in registers: A[m=l16][k=ks*32+quad*8 .. +7], m row = wave*16+l16
  bf16x8 qf[4];
  {
    int grow = qt * 128 + wave * 16 + l16;
    qf[0] = *(const bf16x8*)(qpb + (size_t)grow * 1024 + quad * 8);
    qf[1] = *(const bf16x8*)(qpb + (size_t)grow * 1024 + 32 + quad * 8);
    qf[2] = *(const bf16x8*)(tb0 + (size_t)grow * 64 + quad * 8);
    qf[3] = *(const bf16x8*)(tb0 + (size_t)grow * 64 + 32 + quad * 8);
  }

  // staging index maps (k tile: 2 chunks/thread; v tile: 1 chunk/thread)
  const int kc0_row = tid >> 4,         kc0_cg = tid & 15;
  const int kc1_row = (tid + 512) >> 4, kc1_cg = (tid + 512) & 15;
  const int v_l = tid & 63, v_dvb = (tid >> 6) * 8;

  bf16x8 kr0, kr1, vr;
  {
    const bf16* s0 = (kc0_cg < 8) ? (kpb + (size_t)kc0_row * 1024 + kc0_cg * 8)
                                  : (tb0 + (size_t)kc0_row * 64 + (kc0_cg - 8) * 8);
    const bf16* s1 = (kc1_cg < 8) ? (kpb + (size_t)kc1_row * 1024 + kc1_cg * 8)
                                  : (tb0 + (size_t)kc1_row * 64 + (kc1_cg - 8) * 8);
    kr0 = *(const bf16x8*)s0;
    kr1 = *(const bf16x8*)s1;
    vr  = *(const bf16x8*)&vpb[(size_t)v_l * 1024 + v_dvb];
  }

  f32x4 o[4] = {};
  float l_part[4] = {0.f, 0.f, 0.f, 0.f};

  const float C = 0.12751781f;   // 1/sqrt(128) * log2(e)
  const int qrow_base = qt * 128 + wave * 16 + quad * 4;

  for (int kt = 0; kt < 16; kt++) {
    __syncthreads();   // prior-iter reads of k_s/v_s done
    *(bf16x8*)&k_s[kc0_row][kc0_cg * 8] = kr0;
    *(bf16x8*)&k_s[kc1_row][kc1_cg * 8] = kr1;
    for (int j = 0; j < 8; j++) v_s[v_dvb + j][v_l] = vr[j];
    __syncthreads();

    // S = q_cat @ k_cat^T (K=128); q from registers
    f32x4 s_acc[4] = {};
    for (int ks = 0; ks < 4; ks++) {
      for (int nt = 0; nt < 4; nt++) {
        bf16x8 bfr = *(const bf16x8*)&k_s[nt * 16 + l16][ks * 32 + quad * 8];
        s_acc[nt] = __builtin_amdgcn_mfma_f32_16x16x32_bf16(qf[ks], bfr, s_acc[nt], 0, 0, 0);
      }
    }

    // p = exp2(s*C) (masked -> 0); accumulate l partials; P -> LDS (own rows)
    for (int r = 0; r < 4; r++) {
      unsigned long long wsh = mrow[(size_t)(qrow_base + r) * 16 + kt] >> l16;
      for (int nt = 0; nt < 4; nt++) {
        float arg = s_acc[nt][r] * C;
        if ((wsh >> (nt * 16)) & 1ull) arg = -1e9f;
        float p = __builtin_amdgcn_exp2f(arg);
        l_part[r] += p;
        p_s[wave * 16 + quad * 4 + r][nt * 16 + l16] = (bf16)p;
      }
    }

    // prefetch kt+1 while PV runs
    if (kt < 15) {
      int gl0 = (kt + 1) * 64;
      const bf16* s0 = (kc0_cg < 8) ? (kpb + (size_t)(gl0 + kc0_row) * 1024 + kc0_cg * 8)
                                    : (tb0 + (size_t)(gl0 + kc0_row) * 64 + (kc0_cg - 8) * 8);
      const bf16* s1 = (kc1_cg < 8) ? (kpb + (size_t)(gl0 + kc1_row) * 1024 + kc1_cg * 8)
                                    : (tb0 + (size_t)(gl0 + kc1_row) * 64 + (kc1_cg - 8) * 8);
      kr0 = *(const bf16x8*)s0;
      kr1 = *(const bf16x8*)s1;
      vr  = *(const bf16x8*)&vpb[(size_t)(gl0 + v_l) * 1024 + v_dvb];
    }

    // O += P @ V (K=64)
    for (int ks = 0; ks < 2; ks++) {
      bf16x8 a = *(const bf16x8*)&p_s[wave * 16 + l16][ks * 32 + quad * 8];
      for (int nt = 0; nt < 4; nt++) {
        bf16x8 bfr = *(const bf16x8*)&v_s[nt * 16 + l16][ks * 32 + quad * 8];
        o[nt] = __builtin_amdgcn_mfma_f32_16x16x32_bf16(a, bfr, o[nt], 0, 0, 0);
      }
    }
  }

  float inv_l[4];
  for (int r = 0; r < 4; r++) {
    float s = l_part[r];
    for (int off = 8; off >= 1; off >>= 1) s += __shfl_xor(s, off);
    inv_l[r] = 1.f / fmaxf(s, 1e-30f);
  }
  for (int nt = 0; nt < 4; nt++) {
    int col = h * 64 + nt * 16 + l16;
    for (int r = 0; r < 4; r++) {
      int row = qt * 128 + wave * 16 + quad * 4 + r;
      xout[((size_t)(b * L_SEQ + row)) * 1024 + col] = (bf16)(o[nt][r] * inv_l[r]);
    }
  }
}

// ---------------------------------------------------------------------------
extern "C" void kernel_launch(void* const* d_in, const int* in_sizes, int n_in,
                              void* d_out, int out_size, void* d_ws, size_t ws_size,
                              hipStream_t stream) {
  const float* Q    = (const float*)d_in[0];
  const float* K    = (const float*)d_in[1];
  const float* V    = (const float*)d_in[2];
  const float* T    = (const float*)d_in[3];
  const int*   mask = (const int*)d_in[4];
  const float* WQ = (const float*)d_in[5];
  const float* bQ = (const float*)d_in[6];
  const float* WK = (const float*)d_in[7];
  const float* bK = (const float*)d_in[8];
  const float* WV = (const float*)d_in[9];
  const float* bV = (const float*)d_in[10];
  const float* WM = (const float*)d_in[11];
  const float* bM = (const float*)d_in[12];
  const float* WT = (const float*)d_in[13];
  const float* bT = (const float*)d_in[14];

  const size_t NE = (size_t)B_SZ * NH * L_SEQ * 64;  // 8388608
  bf16* ws16 = (bf16*)d_ws;
  bf16* qp = ws16;                    // bf16 8192x1024
  bf16* kp = ws16 + NE;
  bf16* vp = ws16 + 2 * NE;
  bf16* tb = ws16 + 3 * NE;           // 524288
  unsigned long long* mb64 = (unsigned long long*)(ws16 + 3 * NE + 524288);
  bf16* wq = ws16 + 3 * NE + 1048576;
  bf16* wk = wq + 1048576;
  bf16* wv = wk + 1048576;
  bf16* wm = wv + 1048576;
  bf16* av = wm + 1048576;            // gemm3 V-input scratch, then attn output
  bf16* aq = (bf16*)d_out;            // d_out as A-conversion scratch (dead after gemm3)
  bf16* ak = (bf16*)d_out + NE;
  bf16* xa = av;                      // attn bf16 output reuses av slot
  float* fout = (float*)d_out;        // final GEMM writes d_out directly

  dim3 blk(256);

  prep_k<<<dim3(4096, 4), blk, 0, stream>>>(Q, K, V, aq, ak, av, mask, mb64,
                                            WQ, WK, WV, WM, wq, wk, wv, wm,
                                            T, WT, bT, tb);
  gemm3<<<dim3(8, 64, 3), blk, 0, stream>>>(aq, ak, av, wq, wk, wv, bQ, bK, bV, qp, kp, vp);
  attn<<<dim3(128, 8), dim3(512), 0, stream>>>(qp, kp, vp, tb, mb64, xa);
  gemm16<<<dim3(8, 64), blk, 0, stream>>>(xa, wm, bM, fout, 8192, 1024, 1024);
}